// Round 5
// baseline (122.355 us; speedup 1.0000x reference)
//
#include <hip/hip_runtime.h>
#include <stdint.h>

typedef __attribute__((ext_vector_type(8))) short short8;   // bf16x8 MFMA frag (4 VGPR)
typedef __attribute__((ext_vector_type(4))) float f32x4;    // fp32x4 MFMA acc
typedef unsigned short u16;

#define GROUPS 16
#define MROWS  16384
#define NCH    128

__device__ __forceinline__ u16 f2bf(float f) {
    // fp32 -> bf16 round-to-nearest-even (finite inputs only)
    uint32_t u = __float_as_uint(f);
    u += 0x7FFFu + ((u >> 16) & 1u);
    return (u16)(u >> 16);
}

// ---------------------------------------------------------------------------
// Phase 1: build Qt_bf16[g] in frag-linear chunks: 16B chunk index c*16 + s
// holds Q[g][8s..8s+7][c] (i.e. Qt[c][8s..8s+7]). Q = H_0*...*H_127.
// Unchanged math (passing since R1, ~3us).
// ---------------------------------------------------------------------------
__global__ __launch_bounds__(256) void build_q(const float* __restrict__ w,
                                               u16* __restrict__ qt) {
    __shared__ float wt[128 * 128];   // 64 KiB: wt[i][(r + 4i)&127] = v_i[r]
    const int g   = blockIdx.y;
    const int rb  = blockIdx.x;       // 0..7
    const int tid = threadIdx.x;
    const float* wg = w + (size_t)g * NCH * NCH;   // weight[g][r][i]

    const int ci = tid & 127;
    float den = 0.f;
    for (int r = 0; r < 128; r += 4) {
        float a0 = wg[(r + 0) * 128 + ci];
        float a1 = wg[(r + 1) * 128 + ci];
        float a2 = wg[(r + 2) * 128 + ci];
        float a3 = wg[(r + 3) * 128 + ci];
        den += a0 * a0 + a1 * a1 + a2 * a2 + a3 * a3;
    }
    if (tid < 128) wt[tid] = sqrtf(2.0f / den);
    __syncthreads();
    const float scl = wt[ci];
    __syncthreads();

    {
        const int h = tid >> 7;
        for (int p = 0; p < 64; ++p) {
            int r = 2 * p + h;
            wt[ci * 128 + ((r + 4 * ci) & 127)] = wg[r * 128 + ci] * scl;
        }
    }
    __syncthreads();

    const int t = rb * 16 + (tid >> 4);
    const int s = tid & 15;
    float q[8];
#pragma unroll
    for (int u = 0; u < 2; ++u)
#pragma unroll
        for (int e = 0; e < 4; ++e)
            q[u * 4 + e] = (4 * s + 64 * u + e == t) ? 1.0f : 0.0f;

    const f32x4* wt4 = (const f32x4*)wt;
    for (int i = 0; i < 128; ++i) {
        f32x4 v0 = wt4[i * 32 + ((s + 0  + i) & 31)];
        f32x4 v1 = wt4[i * 32 + ((s + 16 + i) & 31)];
        float pa = q[0] * v0.x + q[1] * v0.y + q[2] * v0.z + q[3] * v0.w;
        float pb = q[4] * v1.x + q[5] * v1.y + q[6] * v1.z + q[7] * v1.w;
        pa += pb;
        pa += __shfl_xor(pa, 1);
        pa += __shfl_xor(pa, 2);
        pa += __shfl_xor(pa, 4);
        pa += __shfl_xor(pa, 8);
        q[0] -= pa * v0.x; q[1] -= pa * v0.y; q[2] -= pa * v0.z; q[3] -= pa * v0.w;
        q[4] -= pa * v1.x; q[5] -= pa * v1.y; q[6] -= pa * v1.z; q[7] -= pa * v1.w;
    }

    // emit frag-linear: chunk (c*16 + s) = Qt[c][8s..8s+7]; here we own
    // column t of Q for rows 4s+64u+e -> scattered u16 stores (fine, tiny)
    u16* qg = qt + (size_t)g * NCH * NCH;
#pragma unroll
    for (int u = 0; u < 2; ++u)
#pragma unroll
        for (int e = 0; e < 4; ++e) {
            int c = 4 * s + 64 * u + e;           // Q row = Qt col-chunk owner
            // element Qt[c][t]: chunk c*16 + (t>>3), elem t&7
            qg[(c * 16 + (t >> 3)) * 8 + (t & 7)] = f2bf(q[u * 4 + e]);
        }
}

// ---------------------------------------------------------------------------
// Phase 2: out[g] = x[g] (16384x128 fp32) * Q[g], bf16 MFMA. NO LDS, NO
// barrier: each wave owns 16 rows. x prefetch (8 x dwordx4) pinned before
// everything by sched_barrier(0) -> exactly one latency exposure per wave.
// Q frags read per-lane straight from global (L1/L2-hot, 16x64B dense per
// instr). Occupancy is VGPR-limited only: launch_bounds(256,4) -> <=128.
// ---------------------------------------------------------------------------
__global__ __launch_bounds__(256, 4) void apply_q(const float* __restrict__ x,
                                                  const u16* __restrict__ qt,
                                                  float* __restrict__ out) {
    const int g   = blockIdx.y;
    const int bx  = blockIdx.x;          // 0..255
    const int tid = threadIdx.x;
    const int wv  = tid >> 6;
    const int l   = tid & 63;
    const int lr  = l & 15;
    const int lb  = l >> 4;

    const size_t row = (size_t)g * MROWS + (size_t)bx * 64 + wv * 16 + lr;
    const float* xlane = x   + row * NCH;
    float*       olane = out + row * NCH;
    const short8* qfrag = (const short8*)(qt + (size_t)g * NCH * NCH);

    // ---- issue this wave's entire x read (8 x 16B/lane), then fence so the
    // compiler cannot sink the loads into the consumer chain.
    f32x4 xv[8];
#pragma unroll
    for (int kb = 0; kb < 4; ++kb) {
        xv[2 * kb + 0] = *(const f32x4*)(xlane + kb * 32 + lb * 8);
        xv[2 * kb + 1] = *(const f32x4*)(xlane + kb * 32 + lb * 8 + 4);
    }
    __builtin_amdgcn_sched_barrier(0);

    // ---- convert to B-frags: lane holds row (wv*16+lr), k = kb*32+lb*8..+7
    short8 afr[4];
#pragma unroll
    for (int kb = 0; kb < 4; ++kb) {
        f32x4 v0 = xv[2 * kb], v1 = xv[2 * kb + 1];
        short8 a;
        a[0] = (short)f2bf(v0.x); a[1] = (short)f2bf(v0.y);
        a[2] = (short)f2bf(v0.z); a[3] = (short)f2bf(v0.w);
        a[4] = (short)f2bf(v1.x); a[5] = (short)f2bf(v1.y);
        a[6] = (short)f2bf(v1.z); a[7] = (short)f2bf(v1.w);
        afr[kb] = a;
    }

    f32x4 acc[8];
#pragma unroll
    for (int nt = 0; nt < 8; ++nt) { f32x4 z = {0.f, 0.f, 0.f, 0.f}; acc[nt] = z; }

#pragma unroll
    for (int kb = 0; kb < 4; ++kb) {
        const int s = kb * 4 + lb;       // this lane's k-chunk index
#pragma unroll
        for (int nt = 0; nt < 8; ++nt) {
            short8 qf = qfrag[(nt * 16 + lr) * 16 + s];   // global, L1-hot
            // A = Q^T frag (row=c_local), B = x frag (col=m_local)
            // D[c][m]: lane&15 = m_local, (lane>>4)*4+reg = c_local
            acc[nt] = __builtin_amdgcn_mfma_f32_16x16x32_bf16(qf, afr[kb], acc[nt], 0, 0, 0);
        }
    }

    // ---- store: row = wv*16+lr, cols nt*16 + lb*4 .. +3 (float4, dense)
#pragma unroll
    for (int nt = 0; nt < 8; ++nt)
        *(f32x4*)(olane + nt * 16 + lb * 4) = acc[nt];
}

extern "C" void kernel_launch(void* const* d_in, const int* in_sizes, int n_in,
                              void* d_out, int out_size, void* d_ws, size_t ws_size,
                              hipStream_t stream) {
    const float* x = (const float*)d_in[0];
    const float* w = (const float*)d_in[1];
    float* out = (float*)d_out;
    u16* qtw = (u16*)d_ws;               // Qt bf16 frag-linear: 512 KiB

    build_q<<<dim3(8, GROUPS), 256, 0, stream>>>(w, qtw);
    apply_q<<<dim3(MROWS / 64, GROUPS), 256, 0, stream>>>(x, qtw, out);
}

// Round 6
// 85.633 us; speedup vs baseline: 1.4288x; 1.4288x over previous
//
#include <hip/hip_runtime.h>
#include <stdint.h>

typedef __attribute__((ext_vector_type(8))) short short8;   // bf16x8 MFMA frag (4 VGPR)
typedef __attribute__((ext_vector_type(4))) float f32x4;    // fp32x4 MFMA acc
typedef unsigned short u16;

#define GROUPS 16
#define MROWS  16384
#define NCH    128
#define TROWS  32              // rows per tile
#define TPB    8               // tiles per block
// grid.x = MROWS / (TROWS*TPB) = 64; grid 64x16 = 1024 blocks, 2 blocks/CU

#define WAITVM(n) asm volatile("s_waitcnt vmcnt(" #n ")" ::: "memory")

__device__ __forceinline__ u16 f2bf(float f) {
    uint32_t u = __float_as_uint(f);
    u += 0x7FFFu + ((u >> 16) & 1u);
    return (u16)(u >> 16);
}

// ---------------------------------------------------------------------------
// Phase 1: build Q in frag-linear bf16 chunks: 16B chunk (c*16 + s) holds
// Qt[c][8s..8s+7] = Q[8s..8s+7][c].  Q = H_0*...*H_127.  Unchanged (passes).
// ---------------------------------------------------------------------------
__global__ __launch_bounds__(256) void build_q(const float* __restrict__ w,
                                               u16* __restrict__ qt) {
    __shared__ float wt[128 * 128];
    const int g   = blockIdx.y;
    const int rb  = blockIdx.x;
    const int tid = threadIdx.x;
    const float* wg = w + (size_t)g * NCH * NCH;

    const int ci = tid & 127;
    float den = 0.f;
    for (int r = 0; r < 128; r += 4) {
        float a0 = wg[(r + 0) * 128 + ci];
        float a1 = wg[(r + 1) * 128 + ci];
        float a2 = wg[(r + 2) * 128 + ci];
        float a3 = wg[(r + 3) * 128 + ci];
        den += a0 * a0 + a1 * a1 + a2 * a2 + a3 * a3;
    }
    if (tid < 128) wt[tid] = sqrtf(2.0f / den);
    __syncthreads();
    const float scl = wt[ci];
    __syncthreads();

    {
        const int h = tid >> 7;
        for (int p = 0; p < 64; ++p) {
            int r = 2 * p + h;
            wt[ci * 128 + ((r + 4 * ci) & 127)] = wg[r * 128 + ci] * scl;
        }
    }
    __syncthreads();

    const int t = rb * 16 + (tid >> 4);
    const int s = tid & 15;
    float q[8];
#pragma unroll
    for (int u = 0; u < 2; ++u)
#pragma unroll
        for (int e = 0; e < 4; ++e)
            q[u * 4 + e] = (4 * s + 64 * u + e == t) ? 1.0f : 0.0f;

    const f32x4* wt4 = (const f32x4*)wt;
    for (int i = 0; i < 128; ++i) {
        f32x4 v0 = wt4[i * 32 + ((s + 0  + i) & 31)];
        f32x4 v1 = wt4[i * 32 + ((s + 16 + i) & 31)];
        float pa = q[0] * v0.x + q[1] * v0.y + q[2] * v0.z + q[3] * v0.w;
        float pb = q[4] * v1.x + q[5] * v1.y + q[6] * v1.z + q[7] * v1.w;
        pa += pb;
        pa += __shfl_xor(pa, 1);
        pa += __shfl_xor(pa, 2);
        pa += __shfl_xor(pa, 4);
        pa += __shfl_xor(pa, 8);
        q[0] -= pa * v0.x; q[1] -= pa * v0.y; q[2] -= pa * v0.z; q[3] -= pa * v0.w;
        q[4] -= pa * v1.x; q[5] -= pa * v1.y; q[6] -= pa * v1.z; q[7] -= pa * v1.w;
    }

    u16* qg = qt + (size_t)g * NCH * NCH;
#pragma unroll
    for (int u = 0; u < 2; ++u)
#pragma unroll
        for (int e = 0; e < 4; ++e) {
            int c = 4 * s + 64 * u + e;
            qg[(c * 16 + (t >> 3)) * 8 + (t & 7)] = f2bf(q[u * 4 + e]);
        }
}

// ---------------------------------------------------------------------------
// Phase 2: out[g] = x[g] * Q[g].  Pipelined streamer (m97/T3+T4 pattern):
// Q 32KB in LDS (staged once); x 16KB/tile double-buffered via
// global_load_lds (can't be sunk by the compiler), pre-swizzled source so
// ds_read_b128 A-frags are conflict-light; raw s_barrier + COUNTED vmcnt(8)
// keeps next tile's loads in flight across the compute phase.
// Waves: wv>>1 = row half (16 rows), wv&1 = col half (64 cols).
// ---------------------------------------------------------------------------
__global__ __launch_bounds__(256) void apply_q(const float* __restrict__ x,
                                               const u16* __restrict__ qt,
                                               float* __restrict__ out) {
    __shared__ __align__(16) char smem[65536];   // [0,32K) Q; 2 x-bufs 16K each
    char* const qbase = smem;
    char* const xbuf0 = smem + 32768;
    char* const xbuf1 = smem + 49152;

    const int g   = blockIdx.y;
    const int bx  = blockIdx.x;          // 0..63, 256 rows per block
    const int tid = threadIdx.x;
    const int wv  = tid >> 6;
    const int l   = tid & 63;
    const int lr  = l & 15;
    const int lb  = l >> 4;
    const int rowHalf = wv >> 1;         // 0/1 -> rows 0-15 / 16-31 of tile
    const int colHalf = wv & 1;          // 0/1 -> cols 0-63 / 64-127

    const char* xg = (const char*)(x + ((size_t)g * MROWS + (size_t)bx * (TROWS * TPB)) * NCH);
    float* og      = out + ((size_t)g * MROWS + (size_t)bx * (TROWS * TPB)) * NCH;

    // ---- stage Q (8 x 16B per thread), frag-linear: lds (s*128+c)*16 <- chunk c*16+s
    {
        const char* qsrc = (const char*)(qt + (size_t)g * NCH * NCH);
#pragma unroll
        for (int p = 0; p < 8; ++p) {
            int f = p * 256 + tid;                       // f = s*128 + c
            int src_chunk = ((f & 127) << 4) + (f >> 7); // c*16 + s
            __builtin_amdgcn_global_load_lds(
                (const __attribute__((address_space(1))) void*)(qsrc + src_chunk * 16),
                (__attribute__((address_space(3))) void*)(qbase + f * 16),
                16, 0, 0);
        }
    }

    // ---- x tile staging: 16KB, 4 x 16B per thread, swizzled SOURCE, linear dest
    auto stage_x = [&](int t, char* buf) {
#pragma unroll
        for (int p = 0; p < 4; ++p) {
            int f   = p * 256 + tid;                     // 0..1023
            int row = f >> 5;                            // 0..31
            int off = ((f & 31) * 16) ^ ((row & 7) << 4);
            __builtin_amdgcn_global_load_lds(
                (const __attribute__((address_space(1))) void*)
                    (xg + (size_t)t * (TROWS * 512) + row * 512 + off),
                (__attribute__((address_space(3))) void*)(buf + f * 16),
                16, 0, 0);
        }
    };

    stage_x(0, xbuf0);
    stage_x(1, xbuf1);
    // per-wave outstanding now: Q(8) + s0(4) + s1(4) = 16

#pragma unroll
    for (int t = 0; t < TPB; ++t) {
        char* cbuf = (t & 1) ? xbuf1 : xbuf0;
        char* nbuf = (t & 1) ? xbuf0 : xbuf1;

        __builtin_amdgcn_s_barrier();          // A: all waves done reading nbuf
        if (t >= 1 && t + 1 < TPB) stage_x(t + 1, nbuf);

        // wait for THIS wave's stage(t) (+Q at t=0); newer-in-flight stays out
        if (t == 0)            WAITVM(4);
        else if (t == TPB - 1) WAITVM(4);
        else                   WAITVM(8);
        __builtin_amdgcn_s_barrier();          // B: tile t fully in LDS
        __builtin_amdgcn_sched_barrier(0);

        // ---- compute tile t: rows rowHalf*16+lr, cols colHalf*64 + nt*16..
        const int r = rowHalf * 16 + lr;
        short8 afr[4];
#pragma unroll
        for (int kb = 0; kb < 4; ++kb) {
            int b0 = r * 512 + ((kb * 128 + lb * 32)      ^ ((r & 7) << 4));
            int b1 = r * 512 + ((kb * 128 + lb * 32 + 16) ^ ((r & 7) << 4));
            f32x4 v0 = *(const f32x4*)(cbuf + b0);
            f32x4 v1 = *(const f32x4*)(cbuf + b1);
            short8 a;
            a[0] = (short)f2bf(v0.x); a[1] = (short)f2bf(v0.y);
            a[2] = (short)f2bf(v0.z); a[3] = (short)f2bf(v0.w);
            a[4] = (short)f2bf(v1.x); a[5] = (short)f2bf(v1.y);
            a[6] = (short)f2bf(v1.z); a[7] = (short)f2bf(v1.w);
            afr[kb] = a;
        }

        f32x4 acc[4];
#pragma unroll
        for (int nt = 0; nt < 4; ++nt) { f32x4 z = {0.f, 0.f, 0.f, 0.f}; acc[nt] = z; }

#pragma unroll
        for (int kb = 0; kb < 4; ++kb) {
            const int s = kb * 4 + lb;
#pragma unroll
            for (int nt = 0; nt < 4; ++nt) {
                const int c = colHalf * 64 + nt * 16 + lr;
                short8 qf = *(const short8*)(qbase + (s * 128 + c) * 16);
                // D[c][m]: m_local = lane&15 (= lr, the row), c_local = lb*4+reg
                acc[nt] = __builtin_amdgcn_mfma_f32_16x16x32_bf16(qf, afr[kb], acc[nt], 0, 0, 0);
            }
        }

        // ---- store: row = t*32 + r; cols colHalf*64 + nt*16 + lb*4 (+0..3)
        float* orow = og + (size_t)(t * TROWS + r) * NCH + colHalf * 64;
#pragma unroll
        for (int nt = 0; nt < 4; ++nt)
            *(f32x4*)(orow + nt * 16 + lb * 4) = acc[nt];
    }
}

extern "C" void kernel_launch(void* const* d_in, const int* in_sizes, int n_in,
                              void* d_out, int out_size, void* d_ws, size_t ws_size,
                              hipStream_t stream) {
    const float* x = (const float*)d_in[0];
    const float* w = (const float*)d_in[1];
    float* out = (float*)d_out;
    u16* qtw = (u16*)d_ws;               // Qt bf16 frag-linear: 512 KiB

    build_q<<<dim3(8, GROUPS), 256, 0, stream>>>(w, qtw);
    apply_q<<<dim3(MROWS / (TROWS * TPB), GROUPS), 256, 0, stream>>>(x, qtw, out);
}